// Round 1
// baseline (16.416 us; speedup 1.0000x reference)
//
#include <hip/hip_runtime.h>

#define SR_HALF    22050.0f
#define N_FREQ     2049
#define N_HARM     301
#define N_CLASSES  722
#define FREQ_STEP  10.7666015625f   // 44100/4096, exactly representable

// Kernel 1: per-row argmax over 722 classes (first-max wins, like jnp.argmax),
// then convert to hz and store into the hz output region.
__global__ void argmax_hz_kernel(const float* __restrict__ pc,
                                 float* __restrict__ hz_out) {
    const int row = blockIdx.x;
    const float* p = pc + (size_t)row * N_CLASSES;
    const int tid = threadIdx.x;

    float best = -3.4e38f;
    int   bidx = 0x7fffffff;
    for (int j = tid; j < N_CLASSES; j += 64) {
        float v = p[j];
        if (v > best) { best = v; bidx = j; }   // strict > keeps earliest index
    }
    // wave64 reduction, tie-break on smaller index
    #pragma unroll
    for (int off = 32; off > 0; off >>= 1) {
        float ov = __shfl_down(best, off);
        int   oi = __shfl_down(bidx, off);
        if (ov > best || (ov == best && oi < bidx)) { best = ov; bidx = oi; }
    }
    if (tid == 0) {
        float hz = 0.0f;
        if (bidx != 0) {
            float midi = 38.0f + (float)(bidx - 1) * 0.0625f;     // /16 exact
            hz = exp2f((midi - 69.0f) * (1.0f / 12.0f)) * 440.0f;
        }
        hz_out[row] = hz;
    }
}

// Kernel 2: R = max_i sqrt(40)/sigma_i  (cutoff radius where exp(-0.5*s^2*d^2)
// drops below ~2e-9). Written to ws[0].
__global__ void radius_kernel(const float* __restrict__ sigma,
                              float* __restrict__ ws) {
    const int tid = threadIdx.x;
    float r = 0.0f;
    for (int i = tid; i < N_HARM; i += 64) {
        float s = fabsf(sigma[i]);
        float ri = (s > 1.0e-30f) ? (6.3245553f / s) : 3.0e38f;
        r = fmaxf(r, ri);
    }
    #pragma unroll
    for (int off = 32; off > 0; off >>= 1)
        r = fmaxf(r, __shfl_down(r, off));
    if (tid == 0) ws[0] = r;
}

// Kernel 3: one thread per (row, freq-bin). Gather the <=3 harmonics whose
// Gaussian support covers this bin.
__global__ void harmonic_kernel(const float* __restrict__ hz_arr,
                                const float* __restrict__ w,
                                const float* __restrict__ sigma,
                                const float* __restrict__ ws,
                                float* __restrict__ out) {
    const int k   = blockIdx.x * blockDim.x + threadIdx.x;
    const int row = blockIdx.y;
    if (k >= N_FREQ) return;

    const float hz = hz_arr[row];
    float acc = 0.0f;
    if (hz > 0.0f && hz <= SR_HALF) {
        const float R      = ws[0];
        const float f      = (float)k * FREQ_STEP;
        const float inv_hz = 1.0f / hz;

        // contiguous harmonic index range with |f - n*hz| <= R
        const float nlo_f = fmaxf(ceilf((f - R) * inv_hz), 1.0f);
        const float nhi_f = fminf(floorf((f + R) * inv_hz), (float)N_HARM);
        const int nlo = (int)nlo_f;
        const int nhi = (int)nhi_f;

        for (int n = nlo; n <= nhi; ++n) {
            const float nf   = (float)n;
            const float mean = hz * nf;          // f32, same as reference
            if (mean > SR_HALF) break;           // reference Nyquist gating
            const float d = f - mean;
            const float s = sigma[n - 1];
            const float c = s * s * 0.5f;        // NOTE: faithful sigma^2/2 MULTIPLY
            acc += __expf(-(d * d) * c) * w[n - 1];
        }
    }
    out[(size_t)row * N_FREQ + k] = acc;
}

extern "C" void kernel_launch(void* const* d_in, const int* in_sizes, int n_in,
                              void* d_out, int out_size, void* d_ws, size_t ws_size,
                              hipStream_t stream) {
    const float* pc  = (const float*)d_in[0];   // [2,256,722]
    const float* w   = (const float*)d_in[1];   // [301]
    const float* sig = (const float*)d_in[2];   // [301]

    float* out    = (float*)d_out;
    const int rows = in_sizes[0] / N_CLASSES;             // 2*256 = 512
    float* hz_out = out + (size_t)rows * N_FREQ;          // hz region after spectrum
    float* ws     = (float*)d_ws;

    argmax_hz_kernel<<<rows, 64, 0, stream>>>(pc, hz_out);
    radius_kernel<<<1, 64, 0, stream>>>(sig, ws);

    dim3 grid((N_FREQ + 255) / 256, rows);
    harmonic_kernel<<<grid, 256, 0, stream>>>(hz_out, w, sig, ws, out);
}

// Round 2
// 12.553 us; speedup vs baseline: 1.3077x; 1.3077x over previous
//
#include <hip/hip_runtime.h>

#define SR_HALF    22050.0f
#define N_FREQ     2049
#define N_HARM     301
#define N_CLASSES  722
#define FREQ_STEP  10.7666015625f   // 44100/4096, exactly representable

// One block per row. Phase 1: argmax over 722 classes + sigma->radius max,
// both in one reduction pass. Phase 2: per-bin harmonic gather.
__global__ void __launch_bounds__(256)
fused_kernel(const float* __restrict__ pc,
             const float* __restrict__ w,
             const float* __restrict__ sigma,
             float* __restrict__ out,
             float* __restrict__ hz_out) {
    const int row  = blockIdx.x;
    const int tid  = threadIdx.x;
    const int lane = tid & 63;
    const int wave = tid >> 6;

    __shared__ float s_best[4];
    __shared__ int   s_idx[4];
    __shared__ float s_r[4];
    __shared__ float s_hz;
    __shared__ float s_R;

    // ---- phase 1a: per-thread partial argmax (strict > keeps earliest idx)
    const float* p = pc + (size_t)row * N_CLASSES;
    float best = -3.4e38f;
    int   bidx = 0x7fffffff;
    for (int j = tid; j < N_CLASSES; j += 256) {
        float v = p[j];
        if (v > best) { best = v; bidx = j; }
    }
    // ---- phase 1b: per-thread partial radius  R_i = sqrt(40)/sigma_i
    float r = 0.0f;
    for (int i = tid; i < N_HARM; i += 256) {
        float s  = fabsf(sigma[i]);
        float ri = (s > 1.0e-30f) ? (6.3245553f / s) : 3.0e38f;
        r = fmaxf(r, ri);
    }
    // ---- wave64 reduction (argmax with index tie-break, plus max-R)
    #pragma unroll
    for (int off = 32; off > 0; off >>= 1) {
        float ov = __shfl_down(best, off);
        int   oi = __shfl_down(bidx, off);
        if (ov > best || (ov == best && oi < bidx)) { best = ov; bidx = oi; }
        r = fmaxf(r, __shfl_down(r, off));
    }
    if (lane == 0) { s_best[wave] = best; s_idx[wave] = bidx; s_r[wave] = r; }
    __syncthreads();
    if (tid == 0) {
        float b  = s_best[0];
        int   bi = s_idx[0];
        float rr = s_r[0];
        #pragma unroll
        for (int wv = 1; wv < 4; ++wv) {
            if (s_best[wv] > b || (s_best[wv] == b && s_idx[wv] < bi)) {
                b = s_best[wv]; bi = s_idx[wv];
            }
            rr = fmaxf(rr, s_r[wv]);
        }
        float hz = 0.0f;
        if (bi != 0) {
            float midi = 38.0f + (float)(bi - 1) * 0.0625f;   // /16 exact
            hz = exp2f((midi - 69.0f) * (1.0f / 12.0f)) * 440.0f;
        }
        s_hz = hz;
        s_R  = rr;
        hz_out[row] = hz;
    }
    __syncthreads();

    // ---- phase 2: per-bin gather of the <=3 harmonics covering this bin
    const float hz = s_hz;
    const float R  = s_R;
    float* orow = out + (size_t)row * N_FREQ;

    if (hz > 0.0f && hz <= SR_HALF) {
        const float inv_hz = 1.0f / hz;
        for (int k = tid; k < N_FREQ; k += 256) {
            const float f = (float)k * FREQ_STEP;
            const float nlo_f = fmaxf(ceilf((f - R) * inv_hz), 1.0f);
            const float nhi_f = fminf(floorf((f + R) * inv_hz), (float)N_HARM);
            float acc = 0.0f;
            for (int n = (int)nlo_f; n <= (int)nhi_f; ++n) {
                const float mean = hz * (float)n;   // f32, same as reference
                if (mean > SR_HALF) break;          // reference Nyquist gating
                const float d = f - mean;
                const float s = sigma[n - 1];
                const float c = s * s * 0.5f;       // faithful sigma^2/2 MULTIPLY
                acc += __expf(-(d * d) * c) * w[n - 1];
            }
            orow[k] = acc;
        }
    } else {
        for (int k = tid; k < N_FREQ; k += 256) orow[k] = 0.0f;
    }
}

extern "C" void kernel_launch(void* const* d_in, const int* in_sizes, int n_in,
                              void* d_out, int out_size, void* d_ws, size_t ws_size,
                              hipStream_t stream) {
    const float* pc  = (const float*)d_in[0];   // [2,256,722]
    const float* w   = (const float*)d_in[1];   // [301]
    const float* sig = (const float*)d_in[2];   // [301]

    float* out     = (float*)d_out;
    const int rows = in_sizes[0] / N_CLASSES;            // 2*256 = 512
    float* hz_out  = out + (size_t)rows * N_FREQ;        // hz region after spectrum

    fused_kernel<<<rows, 256, 0, stream>>>(pc, w, sig, out, hz_out);
}

// Round 3
// 12.265 us; speedup vs baseline: 1.3384x; 1.0234x over previous
//
#include <hip/hip_runtime.h>

#define SR_HALF    22050.0f
#define N_FREQ     2049
#define N_HARM     301
#define N_CLASSES  722
#define FREQ_STEP  10.7666015625f   // 44100/4096, exactly representable

// One block per row (512 rows). Phase 1: float2-vectorized argmax over 722
// classes, sigma/w staged to LDS, sigma->radius folded into the staging pass.
// Phase 2: per-bin gather of the <=3 harmonics covering each bin (Gaussian
// support radius R = sqrt(40)/sigma_min => truncation < 1e-6, threshold 19.76).
__global__ void __launch_bounds__(256)
fused_kernel(const float* __restrict__ pc,
             const float* __restrict__ w,
             const float* __restrict__ sigma,
             float* __restrict__ out,
             float* __restrict__ hz_out) {
    const int row  = blockIdx.x;
    const int tid  = threadIdx.x;
    const int lane = tid & 63;
    const int wave = tid >> 6;

    __shared__ float s_sig[N_HARM];
    __shared__ float s_w[N_HARM];
    __shared__ float s_best[4];
    __shared__ int   s_idx[4];
    __shared__ float s_r[4];
    __shared__ float s_hz;
    __shared__ float s_R;

    // ---- stage sigma/w to LDS + per-thread partial radius (2 iters)
    float r = 0.0f;
    for (int i = tid; i < N_HARM; i += 256) {
        float s = sigma[i];
        float wv = w[i];
        s_sig[i] = s;
        s_w[i]   = wv;
        float sa = fabsf(s);
        float ri = (sa > 1.0e-30f) ? (6.3245553f / sa) : 3.0e38f;
        r = fmaxf(r, ri);
    }

    // ---- per-thread partial argmax, float2 (722 = 361 pairs; base 8B-aligned)
    const float2* p2 = (const float2*)(pc + (size_t)row * N_CLASSES);
    float best = -3.4e38f;
    int   bidx = 0x7fffffff;
    for (int j = tid; j < 361; j += 256) {
        float2 v = p2[j];
        if (v.x > best) { best = v.x; bidx = 2 * j; }
        if (v.y > best) { best = v.y; bidx = 2 * j + 1; }
    }

    // ---- wave64 reduction (argmax w/ index tie-break, plus max-R)
    #pragma unroll
    for (int off = 32; off > 0; off >>= 1) {
        float ov = __shfl_down(best, off);
        int   oi = __shfl_down(bidx, off);
        if (ov > best || (ov == best && oi < bidx)) { best = ov; bidx = oi; }
        r = fmaxf(r, __shfl_down(r, off));
    }
    if (lane == 0) { s_best[wave] = best; s_idx[wave] = bidx; s_r[wave] = r; }
    __syncthreads();
    if (tid == 0) {
        float b  = s_best[0];
        int   bi = s_idx[0];
        float rr = s_r[0];
        #pragma unroll
        for (int wv = 1; wv < 4; ++wv) {
            if (s_best[wv] > b || (s_best[wv] == b && s_idx[wv] < bi)) {
                b = s_best[wv]; bi = s_idx[wv];
            }
            rr = fmaxf(rr, s_r[wv]);
        }
        float hz = 0.0f;
        if (bi != 0) {
            float midi = 38.0f + (float)(bi - 1) * 0.0625f;   // /16 exact
            hz = exp2f((midi - 69.0f) * (1.0f / 12.0f)) * 440.0f;
        }
        s_hz = hz;
        s_R  = rr;
        hz_out[row] = hz;
    }
    __syncthreads();

    // ---- phase 2: per-bin gather from LDS-resident sigma/w
    const float hz = s_hz;
    const float R  = s_R;
    float* orow = out + (size_t)row * N_FREQ;

    if (hz > 0.0f && hz <= SR_HALF) {
        const float inv_hz = 1.0f / hz;
        for (int k = tid; k < N_FREQ; k += 256) {
            const float f = (float)k * FREQ_STEP;
            const float nlo_f = fmaxf(ceilf((f - R) * inv_hz), 1.0f);
            const float nhi_f = fminf(floorf((f + R) * inv_hz), (float)N_HARM);
            float acc = 0.0f;
            for (int n = (int)nlo_f; n <= (int)nhi_f; ++n) {
                const float mean = hz * (float)n;   // f32, same as reference
                if (mean > SR_HALF) break;          // reference Nyquist gating
                const float d = f - mean;
                const float s = s_sig[n - 1];
                const float c = s * s * 0.5f;       // faithful sigma^2/2 MULTIPLY
                acc += __expf(-(d * d) * c) * s_w[n - 1];
            }
            orow[k] = acc;
        }
    } else {
        for (int k = tid; k < N_FREQ; k += 256) orow[k] = 0.0f;
    }
}

extern "C" void kernel_launch(void* const* d_in, const int* in_sizes, int n_in,
                              void* d_out, int out_size, void* d_ws, size_t ws_size,
                              hipStream_t stream) {
    const float* pc  = (const float*)d_in[0];   // [2,256,722]
    const float* w   = (const float*)d_in[1];   // [301]
    const float* sig = (const float*)d_in[2];   // [301]

    float* out     = (float*)d_out;
    const int rows = in_sizes[0] / N_CLASSES;            // 2*256 = 512
    float* hz_out  = out + (size_t)rows * N_FREQ;        // hz region after spectrum

    fused_kernel<<<rows, 256, 0, stream>>>(pc, w, sig, out, hz_out);
}